// Round 15
// baseline (402.176 us; speedup 1.0000x reference)
//
#include <hip/hip_runtime.h>

#define N_NODES 100000
#define N_EDGES 1600000
#define N_LABEL 200000
#define D 128

#define SCAN_BLOCKS ((N_NODES + 255) / 256)   // 391

typedef __attribute__((ext_vector_type(8))) short short8;
typedef __attribute__((ext_vector_type(4))) float f32x4;

// ---- bf16 helpers (round-to-nearest-even) ----
static __device__ __forceinline__ unsigned short f2bf(float f) {
    unsigned u = __float_as_uint(f);
    u += 0x7fffu + ((u >> 16) & 1u);
    return (unsigned short)(u >> 16);
}
static __device__ __forceinline__ float bf2f_lo(unsigned p) {
    return __uint_as_float(p << 16);
}
static __device__ __forceinline__ float bf2f_hi(unsigned p) {
    return __uint_as_float(p & 0xffff0000u);
}

// ------- merged prep: wv/cval + W1/W2 transpose->bf16 + cnt8 zero -------
__global__ void k_prepall(const float* __restrict__ linW, const float* __restrict__ linb,
                          const float* __restrict__ W1, const float* __restrict__ W2,
                          float* __restrict__ wv, float* __restrict__ cval,
                          unsigned short* __restrict__ w1t,
                          unsigned short* __restrict__ w2t,
                          int* __restrict__ cnt8) {
    int b = blockIdx.x;
    if (b == 0) {
        int t = threadIdx.x;
        if (t < 128) {
            float s = 0.f;
            for (int j = 0; j < D; ++j) s += linW[t * D + j];
            wv[t] = s;
        }
        __shared__ float red[128];
        if (t < 128) red[t] = linb[t];
        __syncthreads();
        for (int st = 64; st > 0; st >>= 1) {
            if (t < st) red[t] += red[t + st];
            __syncthreads();
        }
        if (t == 0) *cval = red[0];
    } else if (b <= 64) {
        int i = (b - 1) * 256 + threadIdx.x;   // i < 16384
        int k = i >> 7, n = i & 127;
        w1t[n * D + k] = f2bf(W1[i]);
    } else if (b <= 128) {
        int i = (b - 65) * 256 + threadIdx.x;
        int k = i >> 7, n = i & 127;
        w2t[n * D + k] = f2bf(W2[i]);
    } else {
        int i = (b - 129) * 256 + threadIdx.x;
        if (i < 8 * N_NODES) cnt8[i] = 0;
    }
}

// partitioned in-degree count; atomic returns rank WITHIN partition.
__global__ void k_count(const int* __restrict__ ei, int* __restrict__ cnt8,
                        int* __restrict__ rank) {
    int e = blockIdx.x * 256 + threadIdx.x;
    int p = blockIdx.x & 7;
    if (e < N_EDGES) rank[e] = atomicAdd(&cnt8[p * N_NODES + ei[N_EDGES + e]], 1);
}

// ---------------- CSR build: scan ----------------
__global__ void k_scan1(const int* __restrict__ cnt8, int* __restrict__ offs,
                        int* __restrict__ bsum) {
    __shared__ int sm[256];
    int tid = threadIdx.x;
    int i = blockIdx.x * 256 + tid;
    int v = 0;
    if (i < N_NODES) {
#pragma unroll
        for (int q = 0; q < 8; ++q) v += cnt8[q * N_NODES + i];
    }
    sm[tid] = v;
    __syncthreads();
    for (int st = 1; st < 256; st <<= 1) {
        int add = (tid >= st) ? sm[tid - st] : 0;
        __syncthreads();
        sm[tid] += add;
        __syncthreads();
    }
    if (i < N_NODES) offs[i] = sm[tid] - v;  // exclusive (block-local)
    if (tid == 255) bsum[blockIdx.x] = sm[255];
}

// scan3 (merged scan2): each block reduces bsum[0..blockIdx) itself,
// then writes global offsets + per-partition bases pofs[q][i]
__global__ void k_scan3(int* __restrict__ offs, const int* __restrict__ bsum,
                        const int* __restrict__ cnt8, int* __restrict__ pofs) {
    __shared__ int preSm;
    int tid = threadIdx.x;
    if (tid < 64) {
        int s = 0;
        for (int j = tid; j < (int)blockIdx.x; j += 64) s += bsum[j];
#pragma unroll
        for (int st = 32; st > 0; st >>= 1) s += __shfl_down(s, st, 64);
        if (tid == 0) preSm = s;
    }
    __syncthreads();
    int pre = preSm;
    int i = blockIdx.x * 256 + tid;
    if (i < N_NODES) {
        int base = offs[i] + pre;
        offs[i] = base;
#pragma unroll
        for (int q = 0; q < 8; ++q) {
            pofs[q * N_NODES + i] = base;
            base += cnt8[q * N_NODES + i];
        }
    }
    if (i == 0) offs[N_NODES] = N_EDGES;
}

// atomic-free scatter: pos = pofs[p][dst] + rank[e], p = blockIdx&7
__global__ void k_scatter(const int* __restrict__ ei, const float* __restrict__ ew,
                          const int* __restrict__ pofs, const int* __restrict__ rank,
                          int2* __restrict__ csr) {
    int e = blockIdx.x * 256 + threadIdx.x;
    int p = blockIdx.x & 7;
    if (e < N_EDGES) {
        int d = ei[N_EDGES + e];
        int pos = pofs[p * N_NODES + d] + rank[e];
        csr[pos] = make_int2(ei[e] << 6, __float_as_int(ew[e]));
    }
}

// ------- GEMM layer1 + fused dinv computation -------
// phase0: each wave computes dinv for its 16 rows (deg = 1 + sum raw w over
// csr rows, coalesced lane-parallel read + shfl reduce) -> LDS dsm + global.
// Then standard MFMA tile: H' = dinv_row * bf16(x @ W1).
__global__ __launch_bounds__(256) void k_gemm1d(const float* __restrict__ X,
                                                const unsigned short* __restrict__ Wt,
                                                const int* __restrict__ offs,
                                                const int2* __restrict__ csr,
                                                float* __restrict__ dinv,
                                                unsigned short* __restrict__ H) {
    __shared__ unsigned short xs[64 * 128];
    __shared__ unsigned short wts[128 * 128];
    __shared__ float dsm[64];
    int tid = threadIdx.x;
    int lane = tid & 63;
    int rowBase = blockIdx.x * 64;
    int w = __builtin_amdgcn_readfirstlane(tid >> 6);

    // phase 0: dinv for this block's 64 rows
    for (int t = 0; t < 16; ++t) {
        int node = rowBase + w * 16 + t;       // wave-uniform
        float dv = 0.f;
        if (node < N_NODES) {
            int p0 = offs[node], p1 = offs[node + 1];
            float s = 0.f;
            for (int pp = p0 + lane; pp < p1; pp += 64)
                s += __int_as_float(csr[pp].y);
#pragma unroll
            for (int st = 32; st > 0; st >>= 1) s += __shfl_xor(s, st, 64);
            dv = rsqrtf(1.0f + s);
            if (lane == 0) dinv[node] = dv;
        }
        if (lane == 0) dsm[w * 16 + t] = dv;
    }

    // stage x tile (f32 -> bf16)
#pragma unroll
    for (int i = 0; i < 4; ++i) {
        int idx = tid + i * 256;
        int r = idx >> 4;
        int kc = (idx & 15) << 3;
        int gr = rowBase + r;
        uint4 pk = make_uint4(0, 0, 0, 0);
        if (gr < N_NODES) {
            float4 v0 = *(const float4*)&X[(size_t)gr * D + kc];
            float4 v1 = *(const float4*)&X[(size_t)gr * D + kc + 4];
            pk.x = (unsigned)f2bf(v0.x) | ((unsigned)f2bf(v0.y) << 16);
            pk.y = (unsigned)f2bf(v0.z) | ((unsigned)f2bf(v0.w) << 16);
            pk.z = (unsigned)f2bf(v1.x) | ((unsigned)f2bf(v1.y) << 16);
            pk.w = (unsigned)f2bf(v1.z) | ((unsigned)f2bf(v1.w) << 16);
        }
        *(uint4*)&xs[(r * D + kc) ^ ((r & 7) << 3)] = pk;
    }
#pragma unroll
    for (int i = 0; i < 8; ++i) {
        int idx = tid + i * 256;
        int n = idx >> 4;
        int kc = (idx & 15) << 3;
        uint4 pk = *(const uint4*)&Wt[n * D + kc];
        *(uint4*)&wts[(n * D + kc) ^ ((n & 7) << 3)] = pk;
    }
    __syncthreads();

    int wrow = w * 16;
    int l15 = lane & 15;
    int l4 = (lane >> 4) << 2;

    f32x4 acc[8] = {};
    union FragU { short8 v; uint2 u2[2]; };

#pragma unroll
    for (int kk = 0; kk < 4; ++kk) {
        int kb = kk * 32 + l4;
        int m = wrow + l15;
        FragU a;
        a.u2[0] = *(uint2*)&xs[(m * D + kb) ^ ((m & 7) << 3)];
        a.u2[1] = *(uint2*)&xs[(m * D + kb + 16) ^ ((m & 7) << 3)];
#pragma unroll
        for (int ct = 0; ct < 8; ++ct) {
            int n = ct * 16 + l15;
            FragU b;
            b.u2[0] = *(uint2*)&wts[(n * D + kb) ^ ((n & 7) << 3)];
            b.u2[1] = *(uint2*)&wts[(n * D + kb + 16) ^ ((n & 7) << 3)];
            acc[ct] = __builtin_amdgcn_mfma_f32_16x16x32_bf16(a.v, b.v, acc[ct], 0, 0, 0);
        }
    }

    int rloc = wrow + l4;
    float dn[4];
#pragma unroll
    for (int r = 0; r < 4; ++r) dn[r] = dsm[rloc + r];
#pragma unroll
    for (int ct = 0; ct < 8; ++ct) {
#pragma unroll
        for (int r = 0; r < 4; ++r) {
            int gr = rowBase + rloc + r;
            if (gr < N_NODES)
                H[(size_t)gr * D + ct * 16 + l15] = f2bf(acc[ct][r] * dn[r]);
        }
    }
}

// ------- FUSED agg(layer1) + GEMM(layer2) -------
// Each wave aggregates its 16 nodes (proven 1-wave agg body) into the LDS
// A-tile, then runs its MFMA quadrant: A from LDS, B direct from global w2t
// (32KB, L1-resident). No __syncthreads: each wave reads only its own rows.
// Output: h2' = dinv_row * bf16(relu(dinv*(A·h1'+h1') + b1) @ W2).
__global__ __launch_bounds__(256) void k_agg_gemm(const unsigned* __restrict__ h,
                                                  const float* __restrict__ dinv,
                                                  const int* __restrict__ offs,
                                                  const int2* __restrict__ csr,
                                                  const float* __restrict__ bias,
                                                  const unsigned short* __restrict__ Wt,
                                                  unsigned short* __restrict__ H) {
    __shared__ unsigned short xs[64 * 128];
    int tid = threadIdx.x;
    int lane = tid & 63;
    int rowBase = blockIdx.x * 64;
    int w = __builtin_amdgcn_readfirstlane(tid >> 6);

    // phase A: aggregate 16 nodes per wave -> LDS rows (swizzled)
    float2 bb = *(const float2*)&bias[lane * 2];
    for (int t = 0; t < 16; ++t) {
        int nodeLoc = w * 16 + t;
        int node = rowBase + nodeLoc;          // wave-uniform
        unsigned val = 0;
        if (node < N_NODES) {
            int p0 = offs[node], p1 = offs[node + 1];
            float a0 = 0.f, a1 = 0.f;
            for (int p = p0; p < p1; p += 8) {
                int2 cc[8];
                float ww[8];
#pragma unroll
                for (int k = 0; k < 8; ++k) {
                    int pe = p + k;
                    bool v = pe < p1;               // uniform
                    cc[k] = csr[v ? pe : p0];       // uniform -> s_load
                    ww[k] = v ? __int_as_float(cc[k].y) : 0.f;
                }
                unsigned hh[8];
#pragma unroll
                for (int k = 0; k < 8; ++k)
                    hh[k] = h[(size_t)(unsigned)cc[k].x + lane];
#pragma unroll
                for (int k = 0; k < 8; ++k) {
                    a0 += ww[k] * bf2f_lo(hh[k]);
                    a1 += ww[k] * bf2f_hi(hh[k]);
                }
            }
            unsigned sv = h[(size_t)node * 64 + lane];
            a0 += bf2f_lo(sv);
            a1 += bf2f_hi(sv);
            float dnn = dinv[node];
            a0 = fmaxf(a0 * dnn + bb.x, 0.f);
            a1 = fmaxf(a1 * dnn + bb.y, 0.f);
            val = (unsigned)f2bf(a0) | ((unsigned)f2bf(a1) << 16);
        }
        *(unsigned*)&xs[((nodeLoc * D) + (lane << 1)) ^ ((nodeLoc & 7) << 3)] = val;
    }

    // phase B: MFMA this wave's 16 rows (A rows == rows this wave just wrote;
    // intra-wave LDS dependency only -> compiler's lgkmcnt ordering suffices)
    int wrow = w * 16;
    int l15 = lane & 15;
    int l4 = (lane >> 4) << 2;

    f32x4 acc[8] = {};
    union FragU { short8 v; uint2 u2[2]; };

#pragma unroll
    for (int kk = 0; kk < 4; ++kk) {
        int kb = kk * 32 + l4;
        int m = wrow + l15;
        FragU a;
        a.u2[0] = *(uint2*)&xs[(m * D + kb) ^ ((m & 7) << 3)];
        a.u2[1] = *(uint2*)&xs[(m * D + kb + 16) ^ ((m & 7) << 3)];
#pragma unroll
        for (int ct = 0; ct < 8; ++ct) {
            int n = ct * 16 + l15;
            FragU b;
            b.u2[0] = *(const uint2*)&Wt[n * D + kb];
            b.u2[1] = *(const uint2*)&Wt[n * D + kb + 16];
            acc[ct] = __builtin_amdgcn_mfma_f32_16x16x32_bf16(a.v, b.v, acc[ct], 0, 0, 0);
        }
    }

    int rloc = wrow + l4;
    float dn[4];
#pragma unroll
    for (int r = 0; r < 4; ++r) {
        int gr = rowBase + rloc + r;
        dn[r] = (gr < N_NODES) ? dinv[gr] : 0.f;
    }
#pragma unroll
    for (int ct = 0; ct < 8; ++ct) {
#pragma unroll
        for (int r = 0; r < 4; ++r) {
            int gr = rowBase + rloc + r;
            if (gr < N_NODES)
                H[(size_t)gr * D + ct * 16 + l15] = f2bf(acc[ct][r] * dn[r]);
        }
    }
}

// ---------------- standalone aggregation (layer 2) ----------------
__global__ __launch_bounds__(256) void k_agg(const unsigned* __restrict__ h,
                                             const float* __restrict__ dinv,
                                             const int* __restrict__ offs,
                                             const int2* __restrict__ csr,
                                             const float* __restrict__ bias,
                                             unsigned* __restrict__ out) {
    int lane = threadIdx.x & 63;
    int node = __builtin_amdgcn_readfirstlane(blockIdx.x * 4 + (threadIdx.x >> 6));
    if (node >= N_NODES) return;

    int p0 = offs[node], p1 = offs[node + 1];
    float a0 = 0.f, a1 = 0.f;

    for (int p = p0; p < p1; p += 8) {
        int2 cc[8];
        float ww[8];
#pragma unroll
        for (int k = 0; k < 8; ++k) {
            int pe = p + k;
            bool v = pe < p1;               // uniform
            cc[k] = csr[v ? pe : p0];       // uniform address -> s_load
            ww[k] = v ? __int_as_float(cc[k].y) : 0.f;
        }
        unsigned hh[8];
#pragma unroll
        for (int k = 0; k < 8; ++k)
            hh[k] = h[(size_t)(unsigned)cc[k].x + lane];
#pragma unroll
        for (int k = 0; k < 8; ++k) {
            a0 += ww[k] * bf2f_lo(hh[k]);
            a1 += ww[k] * bf2f_hi(hh[k]);
        }
    }

    unsigned sv = h[(size_t)node * 64 + lane];
    a0 += bf2f_lo(sv);
    a1 += bf2f_hi(sv);
    float dn = dinv[node];
    float2 bb = *(const float2*)&bias[lane * 2];
    a0 = fmaxf(a0 * dn + bb.x, 0.f);
    a1 = fmaxf(a1 * dn + bb.y, 0.f);
    out[(size_t)node * 64 + lane] = (unsigned)f2bf(a0) | ((unsigned)f2bf(a1) << 16);
}

// ---------------- final: res[l] = sum_k o2[a][k]*o2[b][k]*w[k] + c ----------------
__global__ void k_final(const int* __restrict__ eli, const unsigned* __restrict__ o2,
                        const float* __restrict__ wv, const float* __restrict__ cval,
                        float* __restrict__ res) {
    unsigned g = blockIdx.x * 256 + threadIdx.x;
    int l = g >> 5;
    int t = g & 31;
    if (l < N_LABEL) {
        int a = eli[l];
        int b = eli[N_LABEL + l];
        uint2 ua = *(const uint2*)&o2[(size_t)a * 64 + t * 2];
        uint2 ub = *(const uint2*)&o2[(size_t)b * 64 + t * 2];
        float4 w4 = *(const float4*)&wv[t * 4];
        float s = bf2f_lo(ua.x) * bf2f_lo(ub.x) * w4.x
                + bf2f_hi(ua.x) * bf2f_hi(ub.x) * w4.y
                + bf2f_lo(ua.y) * bf2f_lo(ub.y) * w4.z
                + bf2f_hi(ua.y) * bf2f_hi(ub.y) * w4.w;
#pragma unroll
        for (int st = 16; st > 0; st >>= 1) s += __shfl_down(s, st, 32);
        if (t == 0) res[l] = s + *cval;
    }
}

extern "C" void kernel_launch(void* const* d_in, const int* in_sizes, int n_in,
                              void* d_out, int out_size, void* d_ws, size_t ws_size,
                              hipStream_t stream) {
    const float* x    = (const float*)d_in[0];
    const int*   ei   = (const int*)d_in[1];
    const float* ew   = (const float*)d_in[2];
    const int*   eli  = (const int*)d_in[3];
    const float* W1   = (const float*)d_in[4];
    const float* b1   = (const float*)d_in[5];
    const float* W2   = (const float*)d_in[6];
    const float* b2   = (const float*)d_in[7];
    const float* linW = (const float*)d_in[8];
    const float* linb = (const float*)d_in[9];
    float* res = (float*)d_out;

    // workspace layout (csr 8B-aligned)
    float*          ws    = (float*)d_ws;
    float*          dinv  = ws;                              // N
    int*            offs  = (int*)(dinv + N_NODES);          // N+4
    int*            bsum  = offs + N_NODES + 4;              // 512
    int*            cnt8  = bsum + 512;                      // 8*N
    int*            pofs  = cnt8 + 8 * N_NODES;              // 8*N
    int2*           csr   = (int2*)(pofs + 8 * N_NODES);     // E int2 (src*64, raw w)
    unsigned*       h_bf  = (unsigned*)(csr + N_EDGES);      // N*64 uints (bf16 h1')
    unsigned*       h2    = h_bf + (size_t)N_NODES * 64;     // N*64 uints (bf16 h2')
    unsigned*       out2  = h2 + (size_t)N_NODES * 64;       // N*64 uints (bf16)
    float*          wv    = (float*)(out2 + (size_t)N_NODES * 64);  // D
    float*          cval  = wv + D;                          // 1
    unsigned short* w1t   = (unsigned short*)(cval + 1);     // D*D bf16
    unsigned short* w2t   = w1t + D * D;                     // D*D bf16
    int*            rank  = (int*)h2;  // E ints, dead before h2 is written

    // prep (wv/cval, weight transposes, cnt8 zero)
    k_prepall<<<129 + (8 * N_NODES + 255) / 256, 256, 0, stream>>>(
        linW, linb, W1, W2, wv, cval, w1t, w2t, cnt8);

    // CSR: partitioned count (rank-returning), scan (merged), scatter
    k_count<<<(N_EDGES + 255) / 256, 256, 0, stream>>>(ei, cnt8, rank);
    k_scan1<<<SCAN_BLOCKS, 256, 0, stream>>>(cnt8, offs, bsum);
    k_scan3<<<SCAN_BLOCKS, 256, 0, stream>>>(offs, bsum, cnt8, pofs);
    k_scatter<<<(N_EDGES + 255) / 256, 256, 0, stream>>>(ei, ew, pofs, rank, csr);

    const int GB = (N_NODES + 63) / 64;

    // layer 1 GEMM (+ fused dinv): h1' = dinv*(x@W1) bf16
    k_gemm1d<<<GB, 256, 0, stream>>>(x, w1t, offs, csr, dinv, (unsigned short*)h_bf);

    // fused agg(layer1)+GEMM(layer2): h2' = dinv*(relu(dinv*(A·h1'+h1')+b1)@W2)
    k_agg_gemm<<<GB, 256, 0, stream>>>(h_bf, dinv, offs, csr, b1, w2t,
                                       (unsigned short*)h2);

    // layer 2 aggregation: out2 = relu(dinv*(A·h2'+h2') + b2) bf16
    k_agg<<<(N_NODES + 3) / 4, 256, 0, stream>>>(h2, dinv, offs, csr, b2, out2);

    // final
    k_final<<<(N_LABEL * 32 + 255) / 256, 256, 0, stream>>>(eli, out2, wv, cval, res);
}

// Round 16
// 362.928 us; speedup vs baseline: 1.1081x; 1.1081x over previous
//
#include <hip/hip_runtime.h>

#define N_NODES 100000
#define N_EDGES 1600000
#define N_LABEL 200000
#define D 128

#define SCAN_BLOCKS ((N_NODES + 255) / 256)   // 391

typedef __attribute__((ext_vector_type(8))) short short8;
typedef __attribute__((ext_vector_type(4))) float f32x4;

// ---- bf16 helpers (round-to-nearest-even) ----
static __device__ __forceinline__ unsigned short f2bf(float f) {
    unsigned u = __float_as_uint(f);
    u += 0x7fffu + ((u >> 16) & 1u);
    return (unsigned short)(u >> 16);
}
static __device__ __forceinline__ float bf2f_lo(unsigned p) {
    return __uint_as_float(p << 16);
}
static __device__ __forceinline__ float bf2f_hi(unsigned p) {
    return __uint_as_float(p & 0xffff0000u);
}

// ------- merged prep: wv/cval + W1/W2 transpose->bf16 + cnt8 zero -------
__global__ void k_prepall(const float* __restrict__ linW, const float* __restrict__ linb,
                          const float* __restrict__ W1, const float* __restrict__ W2,
                          float* __restrict__ wv, float* __restrict__ cval,
                          unsigned short* __restrict__ w1t,
                          unsigned short* __restrict__ w2t,
                          int* __restrict__ cnt8) {
    int b = blockIdx.x;
    if (b == 0) {
        int t = threadIdx.x;
        if (t < 128) {
            float s = 0.f;
            for (int j = 0; j < D; ++j) s += linW[t * D + j];
            wv[t] = s;
        }
        __shared__ float red[128];
        if (t < 128) red[t] = linb[t];
        __syncthreads();
        for (int st = 64; st > 0; st >>= 1) {
            if (t < st) red[t] += red[t + st];
            __syncthreads();
        }
        if (t == 0) *cval = red[0];
    } else if (b <= 64) {
        int i = (b - 1) * 256 + threadIdx.x;   // i < 16384
        int k = i >> 7, n = i & 127;
        w1t[n * D + k] = f2bf(W1[i]);
    } else if (b <= 128) {
        int i = (b - 65) * 256 + threadIdx.x;
        int k = i >> 7, n = i & 127;
        w2t[n * D + k] = f2bf(W2[i]);
    } else {
        int i = (b - 129) * 256 + threadIdx.x;
        if (i < 8 * N_NODES) cnt8[i] = 0;
    }
}

// partitioned in-degree count; atomic returns rank WITHIN partition.
__global__ void k_count(const int* __restrict__ ei, int* __restrict__ cnt8,
                        int* __restrict__ rank) {
    int e = blockIdx.x * 256 + threadIdx.x;
    int p = blockIdx.x & 7;
    if (e < N_EDGES) rank[e] = atomicAdd(&cnt8[p * N_NODES + ei[N_EDGES + e]], 1);
}

// ---------------- CSR build: scan ----------------
__global__ void k_scan1(const int* __restrict__ cnt8, int* __restrict__ offs,
                        int* __restrict__ bsum) {
    __shared__ int sm[256];
    int tid = threadIdx.x;
    int i = blockIdx.x * 256 + tid;
    int v = 0;
    if (i < N_NODES) {
#pragma unroll
        for (int q = 0; q < 8; ++q) v += cnt8[q * N_NODES + i];
    }
    sm[tid] = v;
    __syncthreads();
    for (int st = 1; st < 256; st <<= 1) {
        int add = (tid >= st) ? sm[tid - st] : 0;
        __syncthreads();
        sm[tid] += add;
        __syncthreads();
    }
    if (i < N_NODES) offs[i] = sm[tid] - v;  // exclusive (block-local)
    if (tid == 255) bsum[blockIdx.x] = sm[255];
}

// scan3 (merged scan2): each block reduces bsum[0..blockIdx) itself,
// then writes global offsets + per-partition bases pofs[q][i]
__global__ void k_scan3(int* __restrict__ offs, const int* __restrict__ bsum,
                        const int* __restrict__ cnt8, int* __restrict__ pofs) {
    __shared__ int preSm;
    int tid = threadIdx.x;
    if (tid < 64) {
        int s = 0;
        for (int j = tid; j < (int)blockIdx.x; j += 64) s += bsum[j];
#pragma unroll
        for (int st = 32; st > 0; st >>= 1) s += __shfl_down(s, st, 64);
        if (tid == 0) preSm = s;
    }
    __syncthreads();
    int pre = preSm;
    int i = blockIdx.x * 256 + tid;
    if (i < N_NODES) {
        int base = offs[i] + pre;
        offs[i] = base;
#pragma unroll
        for (int q = 0; q < 8; ++q) {
            pofs[q * N_NODES + i] = base;
            base += cnt8[q * N_NODES + i];
        }
    }
    if (i == 0) offs[N_NODES] = N_EDGES;
}

// atomic-free scatter: pos = pofs[p][dst] + rank[e], p = blockIdx&7
__global__ void k_scatter(const int* __restrict__ ei, const float* __restrict__ ew,
                          const int* __restrict__ pofs, const int* __restrict__ rank,
                          int2* __restrict__ csr) {
    int e = blockIdx.x * 256 + threadIdx.x;
    int p = blockIdx.x & 7;
    if (e < N_EDGES) {
        int d = ei[N_EDGES + e];
        int pos = pofs[p * N_NODES + d] + rank[e];
        csr[pos] = make_int2(ei[e] << 6, __float_as_int(ew[e]));
    }
}

// ------- GEMM layer1 + fused dinv computation -------
__global__ __launch_bounds__(256) void k_gemm1d(const float* __restrict__ X,
                                                const unsigned short* __restrict__ Wt,
                                                const int* __restrict__ offs,
                                                const int2* __restrict__ csr,
                                                float* __restrict__ dinv,
                                                unsigned short* __restrict__ H) {
    __shared__ unsigned short xs[64 * 128];
    __shared__ unsigned short wts[128 * 128];
    __shared__ float dsm[64];
    int tid = threadIdx.x;
    int lane = tid & 63;
    int rowBase = blockIdx.x * 64;
    int w = __builtin_amdgcn_readfirstlane(tid >> 6);

    // phase 0: dinv for this block's 64 rows
    for (int t = 0; t < 16; ++t) {
        int node = rowBase + w * 16 + t;       // wave-uniform
        float dv = 0.f;
        if (node < N_NODES) {
            int p0 = offs[node], p1 = offs[node + 1];
            float s = 0.f;
            for (int pp = p0 + lane; pp < p1; pp += 64)
                s += __int_as_float(csr[pp].y);
#pragma unroll
            for (int st = 32; st > 0; st >>= 1) s += __shfl_xor(s, st, 64);
            dv = rsqrtf(1.0f + s);
            if (lane == 0) dinv[node] = dv;
        }
        if (lane == 0) dsm[w * 16 + t] = dv;
    }

    // stage x tile (f32 -> bf16)
#pragma unroll
    for (int i = 0; i < 4; ++i) {
        int idx = tid + i * 256;
        int r = idx >> 4;
        int kc = (idx & 15) << 3;
        int gr = rowBase + r;
        uint4 pk = make_uint4(0, 0, 0, 0);
        if (gr < N_NODES) {
            float4 v0 = *(const float4*)&X[(size_t)gr * D + kc];
            float4 v1 = *(const float4*)&X[(size_t)gr * D + kc + 4];
            pk.x = (unsigned)f2bf(v0.x) | ((unsigned)f2bf(v0.y) << 16);
            pk.y = (unsigned)f2bf(v0.z) | ((unsigned)f2bf(v0.w) << 16);
            pk.z = (unsigned)f2bf(v1.x) | ((unsigned)f2bf(v1.y) << 16);
            pk.w = (unsigned)f2bf(v1.z) | ((unsigned)f2bf(v1.w) << 16);
        }
        *(uint4*)&xs[(r * D + kc) ^ ((r & 7) << 3)] = pk;
    }
#pragma unroll
    for (int i = 0; i < 8; ++i) {
        int idx = tid + i * 256;
        int n = idx >> 4;
        int kc = (idx & 15) << 3;
        uint4 pk = *(const uint4*)&Wt[n * D + kc];
        *(uint4*)&wts[(n * D + kc) ^ ((n & 7) << 3)] = pk;
    }
    __syncthreads();

    int wrow = w * 16;
    int l15 = lane & 15;
    int l4 = (lane >> 4) << 2;

    f32x4 acc[8] = {};
    union FragU { short8 v; uint2 u2[2]; };

#pragma unroll
    for (int kk = 0; kk < 4; ++kk) {
        int kb = kk * 32 + l4;
        int m = wrow + l15;
        FragU a;
        a.u2[0] = *(uint2*)&xs[(m * D + kb) ^ ((m & 7) << 3)];
        a.u2[1] = *(uint2*)&xs[(m * D + kb + 16) ^ ((m & 7) << 3)];
#pragma unroll
        for (int ct = 0; ct < 8; ++ct) {
            int n = ct * 16 + l15;
            FragU b;
            b.u2[0] = *(uint2*)&wts[(n * D + kb) ^ ((n & 7) << 3)];
            b.u2[1] = *(uint2*)&wts[(n * D + kb + 16) ^ ((n & 7) << 3)];
            acc[ct] = __builtin_amdgcn_mfma_f32_16x16x32_bf16(a.v, b.v, acc[ct], 0, 0, 0);
        }
    }

    int rloc = wrow + l4;
    float dn[4];
#pragma unroll
    for (int r = 0; r < 4; ++r) dn[r] = dsm[rloc + r];
#pragma unroll
    for (int ct = 0; ct < 8; ++ct) {
#pragma unroll
        for (int r = 0; r < 4; ++r) {
            int gr = rowBase + rloc + r;
            if (gr < N_NODES)
                H[(size_t)gr * D + ct * 16 + l15] = f2bf(acc[ct][r] * dn[r]);
        }
    }
}

// ---------------- MFMA GEMM (layer 2): H'(bf16) = dinv_row * (IN_bf16 @ W) ----
__global__ __launch_bounds__(256) void k_gemm(const unsigned short* __restrict__ IN,
                                              const unsigned short* __restrict__ Wt,
                                              const float* __restrict__ dinv,
                                              unsigned short* __restrict__ H) {
    __shared__ unsigned short xs[64 * 128];
    __shared__ unsigned short wts[128 * 128];
    int tid = threadIdx.x;
    int rowBase = blockIdx.x * 64;

#pragma unroll
    for (int i = 0; i < 4; ++i) {
        int idx = tid + i * 256;
        int r = idx >> 4;
        int kc = (idx & 15) << 3;
        int gr = rowBase + r;
        uint4 pk = make_uint4(0, 0, 0, 0);
        if (gr < N_NODES)
            pk = *(const uint4*)&IN[(size_t)gr * D + kc];
        *(uint4*)&xs[(r * D + kc) ^ ((r & 7) << 3)] = pk;
    }
#pragma unroll
    for (int i = 0; i < 8; ++i) {
        int idx = tid + i * 256;
        int n = idx >> 4;
        int kc = (idx & 15) << 3;
        uint4 pk = *(const uint4*)&Wt[n * D + kc];
        *(uint4*)&wts[(n * D + kc) ^ ((n & 7) << 3)] = pk;
    }
    __syncthreads();

    int lane = tid & 63;
    int wrow = (tid >> 6) * 16;
    int l15 = lane & 15;
    int l4 = (lane >> 4) << 2;

    f32x4 acc[8] = {};
    union FragU { short8 v; uint2 u2[2]; };

#pragma unroll
    for (int kk = 0; kk < 4; ++kk) {
        int kb = kk * 32 + l4;
        int m = wrow + l15;
        FragU a;
        a.u2[0] = *(uint2*)&xs[(m * D + kb) ^ ((m & 7) << 3)];
        a.u2[1] = *(uint2*)&xs[(m * D + kb + 16) ^ ((m & 7) << 3)];
#pragma unroll
        for (int ct = 0; ct < 8; ++ct) {
            int n = ct * 16 + l15;
            FragU b;
            b.u2[0] = *(uint2*)&wts[(n * D + kb) ^ ((n & 7) << 3)];
            b.u2[1] = *(uint2*)&wts[(n * D + kb + 16) ^ ((n & 7) << 3)];
            acc[ct] = __builtin_amdgcn_mfma_f32_16x16x32_bf16(a.v, b.v, acc[ct], 0, 0, 0);
        }
    }

    int rloc = wrow + l4;
    float dn[4];
#pragma unroll
    for (int r = 0; r < 4; ++r) {
        int gr = rowBase + rloc + r;
        dn[r] = (gr < N_NODES) ? dinv[gr] : 0.f;
    }
#pragma unroll
    for (int ct = 0; ct < 8; ++ct) {
#pragma unroll
        for (int r = 0; r < 4; ++r) {
            int gr = rowBase + rloc + r;
            if (gr < N_NODES)
                H[(size_t)gr * D + ct * 16 + l15] = f2bf(acc[ct][r] * dn[r]);
        }
    }
}

// ---------------- fused aggregation: gather(h') + self + dinv + bias + relu ----
// node wave-uniform (readfirstlane) -> CSR walk is scalar work; all 64 lanes
// cover one row (1 uint = 2 feats/lane); 8 independent row-gathers in flight.
__global__ __launch_bounds__(256) void k_agg(const unsigned* __restrict__ h,
                                             const float* __restrict__ dinv,
                                             const int* __restrict__ offs,
                                             const int2* __restrict__ csr,
                                             const float* __restrict__ bias,
                                             unsigned* __restrict__ out) {
    int lane = threadIdx.x & 63;
    int node = __builtin_amdgcn_readfirstlane(blockIdx.x * 4 + (threadIdx.x >> 6));
    if (node >= N_NODES) return;

    int p0 = offs[node], p1 = offs[node + 1];
    float a0 = 0.f, a1 = 0.f;

    for (int p = p0; p < p1; p += 8) {
        int2 cc[8];
        float ww[8];
#pragma unroll
        for (int k = 0; k < 8; ++k) {
            int pe = p + k;
            bool v = pe < p1;               // uniform
            cc[k] = csr[v ? pe : p0];       // uniform address -> s_load
            ww[k] = v ? __int_as_float(cc[k].y) : 0.f;
        }
        unsigned hh[8];
#pragma unroll
        for (int k = 0; k < 8; ++k)
            hh[k] = h[(size_t)(unsigned)cc[k].x + lane];
#pragma unroll
        for (int k = 0; k < 8; ++k) {
            a0 += ww[k] * bf2f_lo(hh[k]);
            a1 += ww[k] * bf2f_hi(hh[k]);
        }
    }

    unsigned sv = h[(size_t)node * 64 + lane];
    a0 += bf2f_lo(sv);
    a1 += bf2f_hi(sv);
    float dn = dinv[node];
    float2 bb = *(const float2*)&bias[lane * 2];
    a0 = fmaxf(a0 * dn + bb.x, 0.f);
    a1 = fmaxf(a1 * dn + bb.y, 0.f);
    out[(size_t)node * 64 + lane] = (unsigned)f2bf(a0) | ((unsigned)f2bf(a1) << 16);
}

// ---------------- final: res[l] = sum_k o2[a][k]*o2[b][k]*w[k] + c ----------------
__global__ void k_final(const int* __restrict__ eli, const unsigned* __restrict__ o2,
                        const float* __restrict__ wv, const float* __restrict__ cval,
                        float* __restrict__ res) {
    unsigned g = blockIdx.x * 256 + threadIdx.x;
    int l = g >> 5;
    int t = g & 31;
    if (l < N_LABEL) {
        int a = eli[l];
        int b = eli[N_LABEL + l];
        uint2 ua = *(const uint2*)&o2[(size_t)a * 64 + t * 2];
        uint2 ub = *(const uint2*)&o2[(size_t)b * 64 + t * 2];
        float4 w4 = *(const float4*)&wv[t * 4];
        float s = bf2f_lo(ua.x) * bf2f_lo(ub.x) * w4.x
                + bf2f_hi(ua.x) * bf2f_hi(ub.x) * w4.y
                + bf2f_lo(ua.y) * bf2f_lo(ub.y) * w4.z
                + bf2f_hi(ua.y) * bf2f_hi(ub.y) * w4.w;
#pragma unroll
        for (int st = 16; st > 0; st >>= 1) s += __shfl_down(s, st, 32);
        if (t == 0) res[l] = s + *cval;
    }
}

extern "C" void kernel_launch(void* const* d_in, const int* in_sizes, int n_in,
                              void* d_out, int out_size, void* d_ws, size_t ws_size,
                              hipStream_t stream) {
    const float* x    = (const float*)d_in[0];
    const int*   ei   = (const int*)d_in[1];
    const float* ew   = (const float*)d_in[2];
    const int*   eli  = (const int*)d_in[3];
    const float* W1   = (const float*)d_in[4];
    const float* b1   = (const float*)d_in[5];
    const float* W2   = (const float*)d_in[6];
    const float* b2   = (const float*)d_in[7];
    const float* linW = (const float*)d_in[8];
    const float* linb = (const float*)d_in[9];
    float* res = (float*)d_out;

    // workspace layout (csr 8B-aligned)
    float*          ws    = (float*)d_ws;
    float*          dinv  = ws;                              // N
    int*            offs  = (int*)(dinv + N_NODES);          // N+4
    int*            bsum  = offs + N_NODES + 4;              // 512
    int*            cnt8  = bsum + 512;                      // 8*N
    int*            pofs  = cnt8 + 8 * N_NODES;              // 8*N
    int2*           csr   = (int2*)(pofs + 8 * N_NODES);     // E int2 (src*64, raw w)
    unsigned*       h_bf  = (unsigned*)(csr + N_EDGES);      // N*64 uints (bf16 h1')
    unsigned*       agg   = h_bf + (size_t)N_NODES * 64;     // N*64 uints (bf16)
    unsigned*       out2  = agg + (size_t)N_NODES * 64;      // N*64 uints (bf16)
    float*          wv    = (float*)(out2 + (size_t)N_NODES * 64);  // D
    float*          cval  = wv + D;                          // 1
    unsigned short* w1t   = (unsigned short*)(cval + 1);     // D*D bf16
    unsigned short* w2t   = w1t + D * D;                     // D*D bf16
    int*            rank  = (int*)agg;  // E ints, dead before agg is written

    // prep (wv/cval, weight transposes, cnt8 zero)
    k_prepall<<<129 + (8 * N_NODES + 255) / 256, 256, 0, stream>>>(
        linW, linb, W1, W2, wv, cval, w1t, w2t, cnt8);

    // CSR: partitioned count (rank-returning), scan (merged), scatter
    k_count<<<(N_EDGES + 255) / 256, 256, 0, stream>>>(ei, cnt8, rank);
    k_scan1<<<SCAN_BLOCKS, 256, 0, stream>>>(cnt8, offs, bsum);
    k_scan3<<<SCAN_BLOCKS, 256, 0, stream>>>(offs, bsum, cnt8, pofs);
    k_scatter<<<(N_EDGES + 255) / 256, 256, 0, stream>>>(ei, ew, pofs, rank, csr);

    const int GB = (N_NODES + 63) / 64;

    // layer 1: GEMM (+ fused dinv): h1' = dinv*(x@W1) bf16; then aggregate
    k_gemm1d<<<GB, 256, 0, stream>>>(x, w1t, offs, csr, dinv, (unsigned short*)h_bf);
    k_agg<<<(N_NODES + 3) / 4, 256, 0, stream>>>(h_bf, dinv, offs, csr, b1, agg);

    // layer 2: GEMM + aggregate
    k_gemm<<<GB, 256, 0, stream>>>((unsigned short*)agg, w2t, dinv,
                                   (unsigned short*)h_bf);
    k_agg<<<(N_NODES + 3) / 4, 256, 0, stream>>>(h_bf, dinv, offs, csr, b2, out2);

    // final
    k_final<<<(N_LABEL * 32 + 255) / 256, 256, 0, stream>>>(eli, out2, wv, cval, res);
}

// Round 17
// 352.175 us; speedup vs baseline: 1.1420x; 1.0305x over previous
//
#include <hip/hip_runtime.h>

#define N_NODES 100000
#define N_EDGES 1600000
#define N_LABEL 200000
#define D 128

#define SCAN_BLOCKS ((N_NODES + 255) / 256)   // 391

typedef __attribute__((ext_vector_type(8))) short short8;
typedef __attribute__((ext_vector_type(4))) float f32x4;

// ---- bf16 helpers (round-to-nearest-even) ----
static __device__ __forceinline__ unsigned short f2bf(float f) {
    unsigned u = __float_as_uint(f);
    u += 0x7fffu + ((u >> 16) & 1u);
    return (unsigned short)(u >> 16);
}
static __device__ __forceinline__ float bf2f_lo(unsigned p) {
    return __uint_as_float(p << 16);
}
static __device__ __forceinline__ float bf2f_hi(unsigned p) {
    return __uint_as_float(p & 0xffff0000u);
}

// ------- merged prep: wv/cval + W1/W2 transpose->bf16 + cnt8 zero -------
__global__ void k_prepall(const float* __restrict__ linW, const float* __restrict__ linb,
                          const float* __restrict__ W1, const float* __restrict__ W2,
                          float* __restrict__ wv, float* __restrict__ cval,
                          unsigned short* __restrict__ w1t,
                          unsigned short* __restrict__ w2t,
                          int* __restrict__ cnt8) {
    int b = blockIdx.x;
    if (b == 0) {
        int t = threadIdx.x;
        if (t < 128) {
            float s = 0.f;
            for (int j = 0; j < D; ++j) s += linW[t * D + j];
            wv[t] = s;
        }
        __shared__ float red[128];
        if (t < 128) red[t] = linb[t];
        __syncthreads();
        for (int st = 64; st > 0; st >>= 1) {
            if (t < st) red[t] += red[t + st];
            __syncthreads();
        }
        if (t == 0) *cval = red[0];
    } else if (b <= 64) {
        int i = (b - 1) * 256 + threadIdx.x;   // i < 16384
        int k = i >> 7, n = i & 127;
        w1t[n * D + k] = f2bf(W1[i]);
    } else if (b <= 128) {
        int i = (b - 65) * 256 + threadIdx.x;
        int k = i >> 7, n = i & 127;
        w2t[n * D + k] = f2bf(W2[i]);
    } else {
        int i = (b - 129) * 256 + threadIdx.x;
        if (i < 8 * N_NODES) cnt8[i] = 0;
    }
}

// partitioned in-degree count; atomic returns rank WITHIN partition.
// partition p = blockIdx&7 (must match k_scatter's mapping).
__global__ void k_count(const int* __restrict__ ei, int* __restrict__ cnt8,
                        int* __restrict__ rank) {
    int e = blockIdx.x * 256 + threadIdx.x;
    int p = blockIdx.x & 7;
    if (e < N_EDGES) rank[e] = atomicAdd(&cnt8[p * N_NODES + ei[N_EDGES + e]], 1);
}

// ---------------- CSR build: scan ----------------
__global__ void k_scan1(const int* __restrict__ cnt8, int* __restrict__ offs,
                        int* __restrict__ bsum) {
    __shared__ int sm[256];
    int tid = threadIdx.x;
    int i = blockIdx.x * 256 + tid;
    int v = 0;
    if (i < N_NODES) {
#pragma unroll
        for (int q = 0; q < 8; ++q) v += cnt8[q * N_NODES + i];
    }
    sm[tid] = v;
    __syncthreads();
    for (int st = 1; st < 256; st <<= 1) {
        int add = (tid >= st) ? sm[tid - st] : 0;
        __syncthreads();
        sm[tid] += add;
        __syncthreads();
    }
    if (i < N_NODES) offs[i] = sm[tid] - v;  // exclusive (block-local)
    if (tid == 255) bsum[blockIdx.x] = sm[255];
}

// scan3 (merged scan2): each block reduces bsum[0..blockIdx) itself,
// then writes global offsets + per-partition bases pofs[q][i]
__global__ void k_scan3(int* __restrict__ offs, const int* __restrict__ bsum,
                        const int* __restrict__ cnt8, int* __restrict__ pofs) {
    __shared__ int preSm;
    int tid = threadIdx.x;
    if (tid < 64) {
        int s = 0;
        for (int j = tid; j < (int)blockIdx.x; j += 64) s += bsum[j];
#pragma unroll
        for (int st = 32; st > 0; st >>= 1) s += __shfl_down(s, st, 64);
        if (tid == 0) preSm = s;
    }
    __syncthreads();
    int pre = preSm;
    int i = blockIdx.x * 256 + tid;
    if (i < N_NODES) {
        int base = offs[i] + pre;
        offs[i] = base;
#pragma unroll
        for (int q = 0; q < 8; ++q) {
            pofs[q * N_NODES + i] = base;
            base += cnt8[q * N_NODES + i];
        }
    }
    if (i == 0) offs[N_NODES] = N_EDGES;
}

// atomic-free scatter: pos = pofs[p][dst] + rank[e], p = blockIdx&7
// csr record: (src*64, RAW weight bits) in one int2 (single 8B store, cached)
__global__ void k_scatter(const int* __restrict__ ei, const float* __restrict__ ew,
                          const int* __restrict__ pofs, const int* __restrict__ rank,
                          int2* __restrict__ csr) {
    int e = blockIdx.x * 256 + threadIdx.x;
    int p = blockIdx.x & 7;
    if (e < N_EDGES) {
        int d = ei[N_EDGES + e];
        int pos = pofs[p * N_NODES + d] + rank[e];
        csr[pos] = make_int2(ei[e] << 6, __float_as_int(ew[e]));
    }
}

// deg[i] = 1 + sum of raw weights over i's CSR rows -> dinv (no atomics)
__global__ void k_degdinv(const int* __restrict__ offs, const int2* __restrict__ csr,
                          float* __restrict__ dinv) {
    int i = blockIdx.x * 256 + threadIdx.x;
    if (i < N_NODES) {
        int p0 = offs[i], p1 = offs[i + 1];
        float s = 1.0f;  // self loop
        for (int p = p0; p < p1; ++p) s += __int_as_float(csr[p].y);
        dinv[i] = rsqrtf(s);
    }
}

// ---------------- MFMA GEMM: H'(bf16) = dinv_row * (IN @ W) ----------------
template <bool IN_F32>
__global__ __launch_bounds__(256) void k_gemm(const void* __restrict__ INp,
                                              const unsigned short* __restrict__ Wt,
                                              const float* __restrict__ dinv,
                                              unsigned short* __restrict__ H) {
    __shared__ unsigned short xs[64 * 128];
    __shared__ unsigned short wts[128 * 128];
    int tid = threadIdx.x;
    int rowBase = blockIdx.x * 64;

#pragma unroll
    for (int i = 0; i < 4; ++i) {
        int idx = tid + i * 256;        // 1024 slots of 8 elems
        int r = idx >> 4;
        int kc = (idx & 15) << 3;
        int gr = rowBase + r;
        uint4 pk = make_uint4(0, 0, 0, 0);
        if (gr < N_NODES) {
            if (IN_F32) {
                const float* X = (const float*)INp;
                float4 v0 = *(const float4*)&X[(size_t)gr * D + kc];
                float4 v1 = *(const float4*)&X[(size_t)gr * D + kc + 4];
                pk.x = (unsigned)f2bf(v0.x) | ((unsigned)f2bf(v0.y) << 16);
                pk.y = (unsigned)f2bf(v0.z) | ((unsigned)f2bf(v0.w) << 16);
                pk.z = (unsigned)f2bf(v1.x) | ((unsigned)f2bf(v1.y) << 16);
                pk.w = (unsigned)f2bf(v1.z) | ((unsigned)f2bf(v1.w) << 16);
            } else {
                pk = *(const uint4*)&((const unsigned short*)INp)[(size_t)gr * D + kc];
            }
        }
        *(uint4*)&xs[(r * D + kc) ^ ((r & 7) << 3)] = pk;
    }
#pragma unroll
    for (int i = 0; i < 8; ++i) {
        int idx = tid + i * 256;        // 2048 slots
        int n = idx >> 4;
        int kc = (idx & 15) << 3;
        uint4 pk = *(const uint4*)&Wt[n * D + kc];
        *(uint4*)&wts[(n * D + kc) ^ ((n & 7) << 3)] = pk;
    }
    __syncthreads();

    int lane = tid & 63;
    int wrow = (tid >> 6) * 16;
    int l15 = lane & 15;
    int l4 = (lane >> 4) << 2;

    f32x4 acc[8] = {};
    union FragU { short8 v; uint2 u2[2]; };

#pragma unroll
    for (int kk = 0; kk < 4; ++kk) {
        int kb = kk * 32 + l4;
        int m = wrow + l15;
        FragU a;
        a.u2[0] = *(uint2*)&xs[(m * D + kb) ^ ((m & 7) << 3)];
        a.u2[1] = *(uint2*)&xs[(m * D + kb + 16) ^ ((m & 7) << 3)];
#pragma unroll
        for (int ct = 0; ct < 8; ++ct) {
            int n = ct * 16 + l15;
            FragU b;
            b.u2[0] = *(uint2*)&wts[(n * D + kb) ^ ((n & 7) << 3)];
            b.u2[1] = *(uint2*)&wts[(n * D + kb + 16) ^ ((n & 7) << 3)];
            acc[ct] = __builtin_amdgcn_mfma_f32_16x16x32_bf16(a.v, b.v, acc[ct], 0, 0, 0);
        }
    }

    int rloc = wrow + l4;
    float dn[4];
#pragma unroll
    for (int r = 0; r < 4; ++r) {
        int gr = rowBase + rloc + r;
        dn[r] = (gr < N_NODES) ? dinv[gr] : 0.f;
    }
#pragma unroll
    for (int ct = 0; ct < 8; ++ct) {
#pragma unroll
        for (int r = 0; r < 4; ++r) {
            int gr = rowBase + rloc + r;
            if (gr < N_NODES)
                H[(size_t)gr * D + ct * 16 + l15] = f2bf(acc[ct][r] * dn[r]);
        }
    }
}

// ---------------- fused aggregation: gather(h') + self + dinv + bias + relu ----
// h' is dinv-prescaled bf16. out[d] = relu(dinv[d]*(sum ew*h'[s] + h'[d]) + b).
// node wave-uniform (readfirstlane) -> CSR walk is scalar work; all 64 lanes
// cover one row (1 uint = 2 feats/lane); 8 independent row-gathers in flight.
__global__ __launch_bounds__(256) void k_agg(const unsigned* __restrict__ h,
                                             const float* __restrict__ dinv,
                                             const int* __restrict__ offs,
                                             const int2* __restrict__ csr,
                                             const float* __restrict__ bias,
                                             unsigned* __restrict__ out) {
    int lane = threadIdx.x & 63;
    int node = __builtin_amdgcn_readfirstlane(blockIdx.x * 4 + (threadIdx.x >> 6));
    if (node >= N_NODES) return;

    int p0 = offs[node], p1 = offs[node + 1];
    float a0 = 0.f, a1 = 0.f;

    for (int p = p0; p < p1; p += 8) {
        int2 cc[8];
        float ww[8];
#pragma unroll
        for (int k = 0; k < 8; ++k) {
            int pe = p + k;
            bool v = pe < p1;               // uniform
            cc[k] = csr[v ? pe : p0];       // uniform address -> s_load
            ww[k] = v ? __int_as_float(cc[k].y) : 0.f;
        }
        unsigned hh[8];
#pragma unroll
        for (int k = 0; k < 8; ++k)
            hh[k] = h[(size_t)(unsigned)cc[k].x + lane];
#pragma unroll
        for (int k = 0; k < 8; ++k) {
            a0 += ww[k] * bf2f_lo(hh[k]);
            a1 += ww[k] * bf2f_hi(hh[k]);
        }
    }

    unsigned sv = h[(size_t)node * 64 + lane];
    a0 += bf2f_lo(sv);
    a1 += bf2f_hi(sv);
    float dn = dinv[node];
    float2 bb = *(const float2*)&bias[lane * 2];
    a0 = fmaxf(a0 * dn + bb.x, 0.f);
    a1 = fmaxf(a1 * dn + bb.y, 0.f);
    out[(size_t)node * 64 + lane] = (unsigned)f2bf(a0) | ((unsigned)f2bf(a1) << 16);
}

// ---------------- final: res[l] = sum_k o2[a][k]*o2[b][k]*w[k] + c ----------------
// 32 lanes per label (uint2 = 4 feats each), 2 labels per wave
__global__ void k_final(const int* __restrict__ eli, const unsigned* __restrict__ o2,
                        const float* __restrict__ wv, const float* __restrict__ cval,
                        float* __restrict__ res) {
    unsigned g = blockIdx.x * 256 + threadIdx.x;
    int l = g >> 5;
    int t = g & 31;
    if (l < N_LABEL) {
        int a = eli[l];
        int b = eli[N_LABEL + l];
        uint2 ua = *(const uint2*)&o2[(size_t)a * 64 + t * 2];
        uint2 ub = *(const uint2*)&o2[(size_t)b * 64 + t * 2];
        float4 w4 = *(const float4*)&wv[t * 4];
        float s = bf2f_lo(ua.x) * bf2f_lo(ub.x) * w4.x
                + bf2f_hi(ua.x) * bf2f_hi(ub.x) * w4.y
                + bf2f_lo(ua.y) * bf2f_lo(ub.y) * w4.z
                + bf2f_hi(ua.y) * bf2f_hi(ub.y) * w4.w;
#pragma unroll
        for (int st = 16; st > 0; st >>= 1) s += __shfl_down(s, st, 32);
        if (t == 0) res[l] = s + *cval;
    }
}

extern "C" void kernel_launch(void* const* d_in, const int* in_sizes, int n_in,
                              void* d_out, int out_size, void* d_ws, size_t ws_size,
                              hipStream_t stream) {
    const float* x    = (const float*)d_in[0];
    const int*   ei   = (const int*)d_in[1];
    const float* ew   = (const float*)d_in[2];
    const int*   eli  = (const int*)d_in[3];
    const float* W1   = (const float*)d_in[4];
    const float* b1   = (const float*)d_in[5];
    const float* W2   = (const float*)d_in[6];
    const float* b2   = (const float*)d_in[7];
    const float* linW = (const float*)d_in[8];
    const float* linb = (const float*)d_in[9];
    float* res = (float*)d_out;

    // workspace layout (csr 8B-aligned)
    float*          ws    = (float*)d_ws;
    float*          dinv  = ws;                              // N
    int*            offs  = (int*)(dinv + N_NODES);          // N+4
    int*            bsum  = offs + N_NODES + 4;              // 512
    int*            cnt8  = bsum + 512;                      // 8*N
    int*            pofs  = cnt8 + 8 * N_NODES;              // 8*N
    int2*           csr   = (int2*)(pofs + 8 * N_NODES);     // E int2 (src*64, raw w)
    unsigned*       h_bf  = (unsigned*)(csr + N_EDGES);      // N*64 uints (bf16 h')
    unsigned*       agg   = h_bf + (size_t)N_NODES * 64;     // N*64 uints (bf16)
    unsigned*       out2  = agg + (size_t)N_NODES * 64;      // N*64 uints (bf16)
    float*          wv    = (float*)(out2 + (size_t)N_NODES * 64);  // D
    float*          cval  = wv + D;                          // 1
    unsigned short* w1t   = (unsigned short*)(cval + 1);     // D*D bf16
    unsigned short* w2t   = w1t + D * D;                     // D*D bf16
    int*            rank  = (int*)agg;  // E ints, dead before agg is written

    // prep (wv/cval, weight transposes, cnt8 zero)
    k_prepall<<<129 + (8 * N_NODES + 255) / 256, 256, 0, stream>>>(
        linW, linb, W1, W2, wv, cval, w1t, w2t, cnt8);

    // CSR: partitioned count (rank-returning), scan (merged), scatter, degrees
    k_count<<<(N_EDGES + 255) / 256, 256, 0, stream>>>(ei, cnt8, rank);
    k_scan1<<<SCAN_BLOCKS, 256, 0, stream>>>(cnt8, offs, bsum);
    k_scan3<<<SCAN_BLOCKS, 256, 0, stream>>>(offs, bsum, cnt8, pofs);
    k_scatter<<<(N_EDGES + 255) / 256, 256, 0, stream>>>(ei, ew, pofs, rank, csr);
    k_degdinv<<<(N_NODES + 255) / 256, 256, 0, stream>>>(offs, csr, dinv);

    const int GB = (N_NODES + 63) / 64;

    // layer 1: h' = dinv*(x@W1) bf16 via MFMA; agg = relu(dinv*(A·h'+h') + b1) bf16
    k_gemm<true><<<GB, 256, 0, stream>>>(x, w1t, dinv, (unsigned short*)h_bf);
    k_agg<<<(N_NODES + 3) / 4, 256, 0, stream>>>(h_bf, dinv, offs, csr, b1, agg);

    // layer 2
    k_gemm<false><<<GB, 256, 0, stream>>>(agg, w2t, dinv, (unsigned short*)h_bf);
    k_agg<<<(N_NODES + 3) / 4, 256, 0, stream>>>(h_bf, dinv, offs, csr, b2, out2);

    // final
    k_final<<<(N_LABEL * 32 + 255) / 256, 256, 0, stream>>>(eli, out2, wv, cval, res);
}